// Round 2
// baseline (44861.996 us; speedup 1.0000x reference)
//
#include <hip/hip_runtime.h>
#include <cmath>

#define BN_SCALE 0.9999950000374997f

// ---------------------------------------------------------------------------
// Fused conv1d (NCH) + bias + maxpool + BN-scale + ReLU.
// grid: (ceil(Lpool/256), O, B), block 256.
__global__ __launch_bounds__(256) void conv_pool_kernel(
    const float* __restrict__ in, const float* __restrict__ w,
    const float* __restrict__ bias, float* __restrict__ out,
    int I, int O, int K, int pad, int Lin, int Lpool, int pool, int act)
{
    __shared__ float xs[1032];   // max seg = 256*4 + 7 - 1 = 1030
    __shared__ float ws[1024];   // max I*K = 256*4
    const int o = blockIdx.y, b = blockIdx.z;
    const int l0 = blockIdx.x * 256;
    const int t = threadIdx.x;

    for (int i = t; i < I * K; i += 256) ws[i] = w[(size_t)o * I * K + i];

    const int l = l0 + t;
    float acc0 = 0.f, acc1 = 0.f, acc2 = 0.f, acc3 = 0.f;
    const int seg = 256 * pool + K - 1;
    const int jbase = l0 * pool - pad;
    const float* inb = in + (size_t)b * I * Lin;

    for (int i = 0; i < I; ++i) {
        __syncthreads();
        for (int s = t; s < seg; s += 256) {
            int j = jbase + s;
            xs[s] = (j >= 0 && j < Lin) ? inb[(size_t)i * Lin + j] : 0.f;
        }
        __syncthreads();
        if (l < Lpool) {
            const int base = t * pool;
            for (int k = 0; k < K; ++k) {
                float wv = ws[i * K + k];
                acc0 += wv * xs[base + 0 + k];
                if (pool > 1) acc1 += wv * xs[base + 1 + k];
                if (pool > 2) { acc2 += wv * xs[base + 2 + k];
                                acc3 += wv * xs[base + 3 + k]; }
            }
        }
    }
    if (l < Lpool) {
        float m = acc0;
        if (pool > 1) m = fmaxf(m, acc1);
        if (pool > 2) { m = fmaxf(m, acc2); m = fmaxf(m, acc3); }
        m += bias[o];
        if (act) m = fmaxf(m * BN_SCALE, 0.f);
        out[((size_t)b * O + o) * Lpool + l] = m;
    }
}

// ---------------------------------------------------------------------------
// OUT[t][b][n] = sum_k X[b][t][k] * W[n][wOff+k] + b1[n] (+ b2[n]).  K = 256.
// grid: (N/256, (T*B)/8), block 256.  8 x-vectors staged in LDS per block.
__global__ __launch_bounds__(256) void feat_gemm_kernel(
    const float* __restrict__ X, int xBs, int xTs,
    const float* __restrict__ W, int ldw, int wOff,
    const float* __restrict__ b1, const float* __restrict__ b2,
    float* __restrict__ OUT, int oTs, int oBs,
    int T, int B)
{
    __shared__ float xsh[8][256];
    const int t = threadIdx.x;
    const int n = blockIdx.x * 256 + t;
    const int m0 = blockIdx.y * 8;

    for (int mi = 0; mi < 8; ++mi) {
        int m = m0 + mi;
        int tt = m / B, bb = m % B;
        xsh[mi][t] = X[(size_t)bb * xBs + (size_t)tt * xTs + t];
    }
    __syncthreads();

    float acc[8] = {0.f,0.f,0.f,0.f,0.f,0.f,0.f,0.f};
    const float* wrow = W + (size_t)n * ldw + wOff;
    for (int k = 0; k < 256; k += 4) {
        const float4 wv = *(const float4*)(wrow + k);
        #pragma unroll
        for (int mi = 0; mi < 8; ++mi) {
            acc[mi] += wv.x * xsh[mi][k]   + wv.y * xsh[mi][k+1]
                     + wv.z * xsh[mi][k+2] + wv.w * xsh[mi][k+3];
        }
    }
    const float bv = b1[n] + (b2 ? b2[n] : 0.f);
    for (int mi = 0; mi < 8; ++mi) {
        int m = m0 + mi;
        int tt = m / B, bb = m % B;
        OUT[(size_t)tt * oTs + (size_t)bb * oBs + n] = acc[mi] + bv;
    }
}

__device__ __forceinline__ float sigm(float x) { return 1.f / (1.f + expf(-x)); }

// ---------------------------------------------------------------------------
// One encoder LSTM step.  grid: (B), block 256 (one thread per hidden j).
__global__ __launch_bounds__(256) void enc_step_kernel(
    const float* __restrict__ gih, const float* __restrict__ whh,
    float* __restrict__ hs, float* __restrict__ cs,
    float* __restrict__ ann, int tstep, int T)
{
    const int b = blockIdx.x, j = threadIdx.x;
    __shared__ float hsh[256];
    hsh[j] = hs[(size_t)b * 256 + j];
    __syncthreads();

    float g[4];
    #pragma unroll
    for (int G = 0; G < 4; ++G) {
        const int o = G * 256 + j;
        const float* wr = whh + (size_t)o * 256;
        float a = gih[(size_t)b * 1024 + o];
        for (int k = 0; k < 256; k += 4) {
            const float4 wv = *(const float4*)(wr + k);
            a += wv.x*hsh[k] + wv.y*hsh[k+1] + wv.z*hsh[k+2] + wv.w*hsh[k+3];
        }
        g[G] = a;
    }
    const float ig = sigm(g[0]);
    const float fg = sigm(g[1]);
    const float gg = tanhf(g[2]);
    const float og = sigm(g[3]);
    const float cn = fg * cs[(size_t)b * 256 + j] + ig * gg;
    const float hn = og * tanhf(cn);
    cs[(size_t)b * 256 + j] = cn;
    hs[(size_t)b * 256 + j] = hn;
    ann[((size_t)b * T + tstep) * 256 + j] = hn;
}

// ---------------------------------------------------------------------------
// One decoder step, fully fused: hsW -> scores -> softmax -> ctx -> gates.
// grid: (B), block 256.
__global__ __launch_bounds__(256) void dec_step_kernel(
    const float* __restrict__ gih, const float* __restrict__ dwih,
    const float* __restrict__ dwhh,
    const float* __restrict__ aw1, const float* __restrict__ aw2,
    const float* __restrict__ ann, const float* __restrict__ annW,
    float* __restrict__ hs, float* __restrict__ cs, int T)
{
    const int b = blockIdx.x, j = threadIdx.x;
    __shared__ float hsh[256], hsWs[256], ctxs[256], ev[256], red[256], aw2s[256];
    hsh[j]  = hs[(size_t)b * 256 + j];
    aw2s[j] = aw2[j];
    __syncthreads();

    // phase 1: hsW[j] = a_w1[j, 0:256] . hs
    {
        const float* wr = aw1 + (size_t)j * 512;
        float a = 0.f;
        for (int k = 0; k < 256; k += 4) {
            const float4 wv = *(const float4*)(wr + k);
            a += wv.x*hsh[k] + wv.y*hsh[k+1] + wv.z*hsh[k+2] + wv.w*hsh[k+3];
        }
        hsWs[j] = a;
    }
    __syncthreads();

    // phase 2: score per time-step (threads 0..T-1)
    float sv = -1e30f;
    if (j < T) {
        const float* aw = annW + ((size_t)b * T + j) * 256;
        float a = 0.f;
        for (int h = 0; h < 256; h += 4) {
            const float4 wv = *(const float4*)(aw + h);
            a += fmaxf(hsWs[h]   + wv.x, 0.f) * aw2s[h]
               + fmaxf(hsWs[h+1] + wv.y, 0.f) * aw2s[h+1]
               + fmaxf(hsWs[h+2] + wv.z, 0.f) * aw2s[h+2]
               + fmaxf(hsWs[h+3] + wv.w, 0.f) * aw2s[h+3];
        }
        sv = a;   // a_b2 dropped: softmax is shift-invariant
    }
    red[j] = sv;
    __syncthreads();
    for (int s = 128; s > 0; s >>= 1) {
        if (j < s) red[j] = fmaxf(red[j], red[j + s]);
        __syncthreads();
    }
    const float mx = red[0];
    __syncthreads();
    const float e = (j < T) ? expf(sv - mx) : 0.f;
    ev[j]  = e;
    red[j] = e;
    __syncthreads();
    for (int s = 128; s > 0; s >>= 1) {
        if (j < s) red[j] += red[j + s];
        __syncthreads();
    }
    const float denom = red[0];

    // phase 3: ctx[j] = sum_t w[t] * ann[b][t][j]
    {
        float a = 0.f;
        const float* ab = ann + (size_t)b * T * 256 + j;
        for (int tt = 0; tt < T; ++tt) a += ev[tt] * ab[(size_t)tt * 256];
        ctxs[j] = a / denom;
    }
    __syncthreads();

    // phase 4: gates = gih + d_wih[:,256:] . ctx + d_whh . hs
    float g[4];
    #pragma unroll
    for (int G = 0; G < 4; ++G) {
        const int o = G * 256 + j;
        float a = gih[(size_t)b * 1024 + o];
        const float* w1 = dwih + (size_t)o * 512 + 256;
        const float* w2 = dwhh + (size_t)o * 256;
        for (int k = 0; k < 256; k += 4) {
            const float4 u = *(const float4*)(w1 + k);
            const float4 v = *(const float4*)(w2 + k);
            a += u.x*ctxs[k] + u.y*ctxs[k+1] + u.z*ctxs[k+2] + u.w*ctxs[k+3];
            a += v.x*hsh[k]  + v.y*hsh[k+1]  + v.z*hsh[k+2]  + v.w*hsh[k+3];
        }
        g[G] = a;
    }
    const float ig = sigm(g[0]);
    const float fg = sigm(g[1]);
    const float gg = tanhf(g[2]);
    const float og = sigm(g[3]);
    const float cn = fg * cs[(size_t)b * 256 + j] + ig * gg;
    const float hn = og * tanhf(cn);
    cs[(size_t)b * 256 + j] = cn;
    hs[(size_t)b * 256 + j] = hn;
}

// ---------------------------------------------------------------------------
// Head: y = relu(hs @ f_w1^T + f_b1); out = sigmoid(y @ f_w2^T + f_b2)
// grid: (B), block 256.
__global__ __launch_bounds__(256) void final_kernel(
    const float* __restrict__ hs,
    const float* __restrict__ fw1, const float* __restrict__ fb1,
    const float* __restrict__ fw2, const float* __restrict__ fb2,
    float* __restrict__ out)
{
    const int b = blockIdx.x, t = threadIdx.x;
    __shared__ float hsh[256], ysh[16];
    hsh[t] = hs[(size_t)b * 256 + t];
    __syncthreads();
    if (t < 16) {
        float a = fb1[t];
        const float* wr = fw1 + (size_t)t * 256;
        for (int k = 0; k < 256; ++k) a += wr[k] * hsh[k];
        ysh[t] = fmaxf(a, 0.f);
    }
    __syncthreads();
    if (t < 8) {
        float a = fb2[t];
        const float* wr = fw2 + (size_t)t * 16;
        for (int k = 0; k < 16; ++k) a += wr[k] * ysh[k];
        out[(size_t)b * 8 + t] = 1.f / (1.f + expf(-a));
    }
}

// ---------------------------------------------------------------------------
extern "C" void kernel_launch(void* const* d_in, const int* in_sizes, int n_in,
                              void* d_out, int out_size, void* d_ws, size_t ws_size,
                              hipStream_t stream)
{
    const float* x     = (const float*)d_in[0];
    const float* e_w1  = (const float*)d_in[1];
    const float* e_b1  = (const float*)d_in[2];
    const float* e_w2  = (const float*)d_in[3];
    const float* e_b2  = (const float*)d_in[4];
    const float* e_w3  = (const float*)d_in[5];
    const float* e_b3  = (const float*)d_in[6];
    const float* e_w5  = (const float*)d_in[7];
    const float* e_b5  = (const float*)d_in[8];
    const float* d_w1  = (const float*)d_in[9];
    const float* d_b1  = (const float*)d_in[10];
    const float* d_w2  = (const float*)d_in[11];
    const float* d_b2  = (const float*)d_in[12];
    const float* d_w3  = (const float*)d_in[13];
    const float* d_b3  = (const float*)d_in[14];
    const float* d_w5  = (const float*)d_in[15];
    const float* d_b5  = (const float*)d_in[16];
    const float* e_wih = (const float*)d_in[17];
    const float* e_whh = (const float*)d_in[18];
    const float* e_bih = (const float*)d_in[19];
    const float* e_bhh = (const float*)d_in[20];
    const float* d_wih = (const float*)d_in[21];
    const float* d_whh = (const float*)d_in[22];
    const float* d_bih = (const float*)d_in[23];
    const float* d_bhh = (const float*)d_in[24];
    const float* a_w1  = (const float*)d_in[25];
    const float* a_b1  = (const float*)d_in[26];
    const float* a_w2  = (const float*)d_in[27];
    // a_b2 (d_in[28]) is irrelevant under softmax
    const float* f_w1  = (const float*)d_in[29];
    const float* f_b1  = (const float*)d_in[30];
    const float* f_w2  = (const float*)d_in[31];
    const float* f_b2  = (const float*)d_in[32];

    const int B = 128, T = 129;

    char* ws = (char*)d_ws;
    size_t off = 0;
    auto alloc = [&](size_t nfloats) {
        float* p = (float*)(ws + off);
        off = (off + nfloats * 4 + 255) & ~(size_t)255;
        return p;
    };

    float* enc_feat = alloc(4227072);      // (B, 256*129)
    float* dec_feat = alloc(4227072);
    float* IH       = alloc(16908288);     // (T, B, 1024) — encIH then decIH
    float* conv_reg = alloc(16752640);     // pool1+pool2+pool3, later ann+annW
    float* hs       = alloc(32768);        // (B,256)
    float* cs       = alloc(32768);

    float* pool1 = conv_reg;
    float* pool2 = pool1 + 8380416;        // (B,64,1023)
    float* pool3 = pool2 + 4177920;        // (B,128,255)
    float* ann   = conv_reg;               // (B,T,256) — after convs are done
    float* annW  = ann + 4227072;          // (B,T,256)

    dim3 blk(256);

    // encoder convnet
    conv_pool_kernel<<<dim3(4,64,B),  blk, 0, stream>>>(x,     e_w1, e_b1, pool1,    64,  64, 7, 2, 4096, 1023, 4, 1);
    conv_pool_kernel<<<dim3(1,128,B), blk, 0, stream>>>(pool1, e_w2, e_b2, pool2,    64, 128, 5, 2, 1023,  255, 4, 1);
    conv_pool_kernel<<<dim3(1,256,B), blk, 0, stream>>>(pool2, e_w3, e_b3, pool3,   128, 256, 3, 2,  255,  128, 2, 1);
    conv_pool_kernel<<<dim3(1,256,B), blk, 0, stream>>>(pool3, e_w5, e_b5, enc_feat,256, 256, 4, 2,  128,  129, 1, 0);
    // decoder convnet
    conv_pool_kernel<<<dim3(4,64,B),  blk, 0, stream>>>(x,     d_w1, d_b1, pool1,    64,  64, 7, 2, 4096, 1023, 4, 1);
    conv_pool_kernel<<<dim3(1,128,B), blk, 0, stream>>>(pool1, d_w2, d_b2, pool2,    64, 128, 5, 2, 1023,  255, 4, 1);
    conv_pool_kernel<<<dim3(1,256,B), blk, 0, stream>>>(pool2, d_w3, d_b3, pool3,   128, 256, 3, 2,  255,  128, 2, 1);
    conv_pool_kernel<<<dim3(1,256,B), blk, 0, stream>>>(pool3, d_w5, d_b5, dec_feat,256, 256, 4, 2,  128,  129, 1, 0);

    hipMemsetAsync(hs, 0, 32768 * 4, stream);
    hipMemsetAsync(cs, 0, 32768 * 4, stream);

    // encIH[t][b][:] = enc_feat[b][t][:] @ e_wih^T + e_bih + e_bhh
    feat_gemm_kernel<<<dim3(4,2064), blk, 0, stream>>>(enc_feat, 33024, 256,
        e_wih, 256, 0, e_bih, e_bhh, IH, 131072, 1024, T, B);

    for (int t = 0; t < T; ++t)
        enc_step_kernel<<<dim3(B), blk, 0, stream>>>(IH + (size_t)t * 131072,
            e_whh, hs, cs, ann, t, T);

    // annW[b][t][:] = ann[b][t][:] @ a_w1[:,256:]^T + a_b1
    feat_gemm_kernel<<<dim3(1,2064), blk, 0, stream>>>(ann, 33024, 256,
        a_w1, 512, 256, a_b1, nullptr, annW, 256, 33024, T, B);

    // decIH[t][b][:] = dec_feat[b][t][:] @ d_wih[:,:256]^T + d_bih + d_bhh
    feat_gemm_kernel<<<dim3(4,2064), blk, 0, stream>>>(dec_feat, 33024, 256,
        d_wih, 512, 0, d_bih, d_bhh, IH, 131072, 1024, T, B);

    for (int t = 0; t < T; ++t)
        dec_step_kernel<<<dim3(B), blk, 0, stream>>>(IH + (size_t)t * 131072,
            d_wih, d_whh, a_w1, a_w2, ann, annW, hs, cs, T);

    final_kernel<<<dim3(B), blk, 0, stream>>>(hs, f_w1, f_b1, f_w2, f_b2, (float*)d_out);

    (void)in_sizes; (void)n_in; (void)out_size; (void)ws_size;
}

// Round 3
// 19007.396 us; speedup vs baseline: 2.3602x; 2.3602x over previous
//
#include <hip/hip_runtime.h>
#include <cmath>

#define BN_SCALE 0.9999950000374997f

__device__ __forceinline__ float sigm(float x) { return 1.f / (1.f + __expf(-x)); }

// ---------------------------------------------------------------------------
// Device-scope grid barrier (monotonic counter; all blocks co-resident).
__device__ __forceinline__ void gsync(unsigned* bar, unsigned target) {
    __syncthreads();
    if (threadIdx.x == 0) {
        __threadfence();
        atomicAdd(bar, 1u);
        while (__hip_atomic_load(bar, __ATOMIC_RELAXED, __HIP_MEMORY_SCOPE_AGENT) < target)
            __builtin_amdgcn_s_sleep(2);
        __threadfence();
    }
    __syncthreads();
}

// ---------------------------------------------------------------------------
// Conv1d (NCH) + bias + maxpool + BN-scale + ReLU, input-chunk stationary.
// Thread owns 4 consecutive pre-pool positions (pool is thread-local).
// grid: (ceil(Lpool/LC), B), block 256.
template<int I, int K, int POOL, int O4, int OPAR, int IC, bool ACT>
__global__ __launch_bounds__(256) void conv2k(
    const float* __restrict__ in, const float* __restrict__ w,
    const float* __restrict__ bias, float* __restrict__ out,
    int O, int Lin, int Lpool)
{
    constexpr int TLP = 256 / OPAR;
    constexpr int NLP = TLP * 4;          // pre-pool positions per chunk
    constexpr int LC  = NLP / POOL;       // pool outputs per chunk
    constexpr int SEG = NLP + K - 1;
    constexpr int PW  = O4 * OPAR;        // output channels per pass
    constexpr int ICH = I / IC;
    __shared__ float xs[IC * SEG];
    __shared__ float ws[PW * IC * K];

    const int chunk = blockIdx.x, b = blockIdx.y, tid = threadIdx.x;
    const int l0 = chunk * LC;
    const int jbase = chunk * NLP - 2;    // pad = 2 for every layer
    const int tlp = tid % TLP, og = tid / TLP;
    const int lp0 = tlp * 4;
    const int npass = O / PW;
    const float* inb = in + (size_t)b * I * Lin;

    for (int p = 0; p < npass; ++p) {
        float acc[O4][4];
        #pragma unroll
        for (int oo = 0; oo < O4; ++oo)
            #pragma unroll
            for (int j = 0; j < 4; ++j) acc[oo][j] = 0.f;

        for (int c = 0; c < ICH; ++c) {
            __syncthreads();   // protect xs/ws from previous pass readers
            for (int idx = tid; idx < PW * IC * K; idx += 256) {
                int oo = idx / (IC * K); int rem = idx % (IC * K);
                int ii = rem / K; int k = rem % K;
                ws[idx] = w[(size_t)((p * PW + oo) * I + c * IC + ii) * K + k];
            }
            if (ICH > 1 || p == 0) {
                for (int idx = tid; idx < IC * SEG; idx += 256) {
                    int ii = idx / SEG, s = idx % SEG;
                    int j = jbase + s;
                    float v = 0.f;
                    if (j >= 0 && j < Lin) v = inb[(size_t)(c * IC + ii) * Lin + j];
                    xs[idx] = v;
                }
            }
            __syncthreads();
            for (int ii = 0; ii < IC; ++ii) {
                float xv[K + 3];
                #pragma unroll
                for (int k = 0; k < K + 3; ++k) xv[k] = xs[ii * SEG + lp0 + k];
                #pragma unroll
                for (int oo = 0; oo < O4; ++oo) {
                    const float* wr = &ws[((og * O4 + oo) * IC + ii) * K];
                    #pragma unroll
                    for (int k = 0; k < K; ++k) {
                        float wv = wr[k];
                        acc[oo][0] += wv * xv[k];
                        acc[oo][1] += wv * xv[k + 1];
                        acc[oo][2] += wv * xv[k + 2];
                        acc[oo][3] += wv * xv[k + 3];
                    }
                }
            }
        }
        #pragma unroll
        for (int oo = 0; oo < O4; ++oo) {
            int o = p * PW + og * O4 + oo;
            float bv = bias[o];
            #pragma unroll
            for (int wnd = 0; wnd < 4 / POOL; ++wnd) {
                float m = acc[oo][wnd * POOL];
                #pragma unroll
                for (int q = 1; q < POOL; ++q) m = fmaxf(m, acc[oo][wnd * POOL + q]);
                int l = l0 + lp0 / POOL + wnd;
                if (l < Lpool) {
                    float v = m + bv;
                    if (ACT) v = fmaxf(v * BN_SCALE, 0.f);
                    out[((size_t)b * O + o) * Lpool + l] = v;
                }
            }
        }
    }
}

// ---------------------------------------------------------------------------
// Small transposes: out[k*N + n] = in[n*ldin + off + k].  grid: N blocks.
__global__ __launch_bounds__(256) void transpose_kt(
    const float* __restrict__ in, float* __restrict__ out, int N, int ldin, int off)
{
    int idx = blockIdx.x * 256 + threadIdx.x;
    int k = idx / N, n = idx % N;
    out[idx] = in[(size_t)n * ldin + off + k];
}

// a_w1[:, :256] packed as [k4][h][4] for coalesced float4 per-k4 reads.
__global__ __launch_bounds__(256) void pack_aw1hs(
    const float* __restrict__ aw1, float* __restrict__ out)
{
    int idx = blockIdx.x * 256 + threadIdx.x;     // < 65536
    int c = idx & 3, h = (idx >> 2) & 255, k4 = idx >> 10;
    out[idx] = aw1[(size_t)h * 512 + k4 * 4 + c];
}

// ---------------------------------------------------------------------------
// OUT[t][b][n] = X[b][t*256+k] . WT[k][n] + b1[n] (+b2[n]).  K=256 fixed.
// Block: 16 m-rows (fixed t, 16 consecutive b), all N.  grid: 1032.
template<int N>
__global__ __launch_bounds__(256) void gemm16(
    const float* __restrict__ X, const float* __restrict__ WT,
    const float* __restrict__ b1, const float* __restrict__ b2,
    float* __restrict__ OUT, int outT, int outB)
{
    constexpr int NL = N / 4;
    constexpr int MS = N >> 6;     // 16 for N=1024, 4 for N=256
    __shared__ float xsh[16][257];
    const int m0 = blockIdx.x * 16;
    const int tt = m0 >> 7, bb0 = m0 & 127;
    const int tid = threadIdx.x;
    for (int it = 0; it < 16; ++it)
        xsh[it][tid] = X[(size_t)(bb0 + it) * 33024 + tt * 256 + tid];
    __syncthreads();
    const int mg = tid / NL, nl = tid % NL;
    float4 acc[MS];
    #pragma unroll
    for (int i = 0; i < MS; ++i) acc[i] = make_float4(0.f, 0.f, 0.f, 0.f);
    for (int k = 0; k < 256; ++k) {
        float4 wv = *(const float4*)(WT + (size_t)k * N + nl * 4);
        #pragma unroll
        for (int ms = 0; ms < MS; ++ms) {
            float s = xsh[mg * MS + ms][k];
            acc[ms].x += wv.x * s; acc[ms].y += wv.y * s;
            acc[ms].z += wv.z * s; acc[ms].w += wv.w * s;
        }
    }
    float4 bv = *(const float4*)(b1 + nl * 4);
    if (b2) {
        float4 b2v = *(const float4*)(b2 + nl * 4);
        bv.x += b2v.x; bv.y += b2v.y; bv.z += b2v.z; bv.w += b2v.w;
    }
    #pragma unroll
    for (int ms = 0; ms < MS; ++ms) {
        int mi = mg * MS + ms;
        float4 v = acc[ms];
        v.x += bv.x; v.y += bv.y; v.z += bv.z; v.w += bv.w;
        *(float4*)(OUT + (size_t)tt * outT + (size_t)(bb0 + mi) * outB + nl * 4) = v;
    }
}

// ---------------------------------------------------------------------------
// Persistent encoder LSTM: 129 steps, weight-stationary whh slices in LDS,
// cs in registers, hs ping-pong, 1 grid barrier per step.
// grid 256 = 32 j-slices x 8 batch-groups, block 256.
__global__ __launch_bounds__(256) void enc_persist(
    const float* __restrict__ IH, const float* __restrict__ whh,
    float* __restrict__ hs0, float* __restrict__ hs1,
    float* __restrict__ cs_out, float* __restrict__ ann, unsigned* __restrict__ bar)
{
    const int blk = blockIdx.x, tid = threadIdx.x;
    const int jg = blk & 31, bg = blk >> 5;
    __shared__ float whh_sl[32 * 260];
    __shared__ float hs_l[16 * 260];
    __shared__ float g_l[16 * 33];
    for (int r = 0; r < 32; ++r) {
        int o = (r >> 3) * 256 + jg * 8 + (r & 7);
        whh_sl[r * 260 + tid] = whh[(size_t)o * 256 + tid];
    }
    float cs_r = 0.f;
    unsigned phase = 0;
    __syncthreads();
    for (int step = 0; step < 129; ++step) {
        const float* cur = (step & 1) ? hs1 : hs0;
        float* nxt = (step & 1) ? hs0 : hs1;
        for (int it = 0; it < 16; ++it)
            hs_l[it * 260 + tid] = cur[(bg * 16 + it) * 256 + tid];
        __syncthreads();
        const int bb = tid >> 4, r0 = tid & 15;
        #pragma unroll
        for (int half = 0; half < 2; ++half) {
            int r = r0 + half * 16;
            int o = (r >> 3) * 256 + jg * 8 + (r & 7);
            float a = IH[(size_t)step * 131072 + (size_t)(bg * 16 + bb) * 1024 + o];
            const float* wr = &whh_sl[r * 260];
            const float* hr = &hs_l[bb * 260];
            for (int k4 = 0; k4 < 64; ++k4) {
                float4 w4 = *(const float4*)(wr + k4 * 4);
                float4 h4 = *(const float4*)(hr + k4 * 4);
                a += w4.x * h4.x + w4.y * h4.y + w4.z * h4.z + w4.w * h4.w;
            }
            g_l[bb * 33 + r] = a;
        }
        __syncthreads();
        if (tid < 128) {
            int bb2 = tid >> 3, jj = tid & 7;
            float gi = g_l[bb2 * 33 + jj],      gf = g_l[bb2 * 33 + 8 + jj];
            float gg = g_l[bb2 * 33 + 16 + jj], go = g_l[bb2 * 33 + 24 + jj];
            float cn = sigm(gf) * cs_r + sigm(gi) * tanhf(gg);
            float hn = sigm(go) * tanhf(cn);
            cs_r = cn;
            int b = bg * 16 + bb2, j = jg * 8 + jj;
            nxt[b * 256 + j] = hn;
            ann[(size_t)b * 33024 + step * 256 + j] = hn;
            if (step == 128) cs_out[b * 256 + j] = cn;
        }
        gsync(bar, 256u * (++phase));
    }
}

// ---------------------------------------------------------------------------
// Persistent decoder: attention (blocks 0..127, 1 block per batch) +
// gates (all 256 blocks, weight-stationary), 2 grid barriers per step.
__global__ __launch_bounds__(256) void dec_persist(
    const float* __restrict__ IH, const float* __restrict__ dwih,
    const float* __restrict__ dwhh, const float* __restrict__ awhs4,
    const float* __restrict__ aw2, const float* __restrict__ ann,
    const float* __restrict__ annW, float* __restrict__ ctx_g,
    float* __restrict__ hs0, float* __restrict__ hs1,
    const float* __restrict__ cs_in, unsigned* __restrict__ bar)
{
    const int blk = blockIdx.x, tid = threadIdx.x;
    const int jg = blk & 31, bg = blk >> 5;
    __shared__ float wih_sl[32 * 260];
    __shared__ float whh_sl[32 * 260];
    __shared__ float hs_l[16 * 260];
    __shared__ float ctx_l[16 * 260];
    __shared__ float g_l[16 * 33];
    __shared__ float hs_a[256], hsW_l[256], aw2_l[256], evs[256], red[256];

    for (int r = 0; r < 32; ++r) {
        int o = (r >> 3) * 256 + jg * 8 + (r & 7);
        wih_sl[r * 260 + tid] = dwih[(size_t)o * 512 + 256 + tid];
        whh_sl[r * 260 + tid] = dwhh[(size_t)o * 256 + tid];
    }
    aw2_l[tid] = aw2[tid];
    float cs_r = 0.f;
    if (tid < 128)
        cs_r = cs_in[(size_t)(bg * 16 + (tid >> 3)) * 256 + jg * 8 + (tid & 7)];
    unsigned phase = 0;
    __syncthreads();

    for (int step = 0; step < 129; ++step) {
        const float* cur = (step & 1) ? hs1 : hs0;
        float* nxt = (step & 1) ? hs0 : hs1;
        if (blk < 128) {                                   // attention for batch blk
            hs_a[tid] = cur[blk * 256 + tid];
            __syncthreads();
            float a = 0.f;
            for (int k4 = 0; k4 < 64; ++k4) {
                float4 wv = *(const float4*)(awhs4 + (size_t)k4 * 1024 + tid * 4);
                float4 hv = *(const float4*)(&hs_a[k4 * 4]);
                a += wv.x * hv.x + wv.y * hv.y + wv.z * hv.z + wv.w * hv.w;
            }
            hsW_l[tid] = a;
            __syncthreads();
            float sv = -3.0e38f;
            if (tid < 129) {
                const float* ar = annW + (size_t)blk * 33024 + tid * 256;
                float s = 0.f;
                for (int h4 = 0; h4 < 64; ++h4) {
                    float4 av = *(const float4*)(ar + h4 * 4);
                    s += fmaxf(hsW_l[h4*4+0] + av.x, 0.f) * aw2_l[h4*4+0];
                    s += fmaxf(hsW_l[h4*4+1] + av.y, 0.f) * aw2_l[h4*4+1];
                    s += fmaxf(hsW_l[h4*4+2] + av.z, 0.f) * aw2_l[h4*4+2];
                    s += fmaxf(hsW_l[h4*4+3] + av.w, 0.f) * aw2_l[h4*4+3];
                }
                sv = s;                                    // a_b2 dropped (softmax-invariant)
            }
            red[tid] = sv; __syncthreads();
            for (int s2 = 128; s2 > 0; s2 >>= 1) {
                if (tid < s2) red[tid] = fmaxf(red[tid], red[tid + s2]);
                __syncthreads();
            }
            float mx = red[0]; __syncthreads();
            float e = (tid < 129) ? __expf(sv - mx) : 0.f;
            evs[tid] = e; red[tid] = e; __syncthreads();
            for (int s2 = 128; s2 > 0; s2 >>= 1) {
                if (tid < s2) red[tid] += red[tid + s2];
                __syncthreads();
            }
            float inv = 1.f / red[0];
            float c = 0.f;
            const float* ab = ann + (size_t)blk * 33024 + tid;
            for (int t2 = 0; t2 < 129; ++t2) c += evs[t2] * ab[(size_t)t2 * 256];
            ctx_g[blk * 256 + tid] = c * inv;
        }
        gsync(bar, 256u * (++phase));
        // gate phase (all blocks)
        for (int it = 0; it < 16; ++it) {
            hs_l[it * 260 + tid]  = cur[(bg * 16 + it) * 256 + tid];
            ctx_l[it * 260 + tid] = ctx_g[(bg * 16 + it) * 256 + tid];
        }
        __syncthreads();
        {
            const int bb = tid >> 4, r0 = tid & 15;
            const float* hr = &hs_l[bb * 260];
            const float* cr = &ctx_l[bb * 260];
            #pragma unroll
            for (int half = 0; half < 2; ++half) {
                int r = r0 + half * 16;
                int o = (r >> 3) * 256 + jg * 8 + (r & 7);
                float a = IH[(size_t)step * 131072 + (size_t)(bg * 16 + bb) * 1024 + o];
                const float* w1 = &wih_sl[r * 260];
                const float* w2 = &whh_sl[r * 260];
                for (int k4 = 0; k4 < 64; ++k4) {
                    float4 u  = *(const float4*)(w1 + k4 * 4);
                    float4 cv = *(const float4*)(cr + k4 * 4);
                    float4 v  = *(const float4*)(w2 + k4 * 4);
                    float4 hv = *(const float4*)(hr + k4 * 4);
                    a += u.x * cv.x + u.y * cv.y + u.z * cv.z + u.w * cv.w;
                    a += v.x * hv.x + v.y * hv.y + v.z * hv.z + v.w * hv.w;
                }
                g_l[bb * 33 + r] = a;
            }
        }
        __syncthreads();
        if (tid < 128) {
            int bb2 = tid >> 3, jj = tid & 7;
            float gi = g_l[bb2 * 33 + jj],      gf = g_l[bb2 * 33 + 8 + jj];
            float gg = g_l[bb2 * 33 + 16 + jj], go = g_l[bb2 * 33 + 24 + jj];
            float cn = sigm(gf) * cs_r + sigm(gi) * tanhf(gg);
            float hn = sigm(go) * tanhf(cn);
            cs_r = cn;
            nxt[(bg * 16 + bb2) * 256 + jg * 8 + jj] = hn;
        }
        gsync(bar, 256u * (++phase));
    }
}

// ---------------------------------------------------------------------------
__global__ __launch_bounds__(256) void final_kernel(
    const float* __restrict__ hs,
    const float* __restrict__ fw1, const float* __restrict__ fb1,
    const float* __restrict__ fw2, const float* __restrict__ fb2,
    float* __restrict__ out)
{
    const int b = blockIdx.x, t = threadIdx.x;
    __shared__ float hsh[256], ysh[16];
    hsh[t] = hs[(size_t)b * 256 + t];
    __syncthreads();
    if (t < 16) {
        float a = fb1[t];
        const float* wr = fw1 + (size_t)t * 256;
        for (int k = 0; k < 256; ++k) a += wr[k] * hsh[k];
        ysh[t] = fmaxf(a, 0.f);
    }
    __syncthreads();
    if (t < 8) {
        float a = fb2[t];
        const float* wr = fw2 + (size_t)t * 16;
        for (int k = 0; k < 16; ++k) a += wr[k] * ysh[k];
        out[(size_t)b * 8 + t] = 1.f / (1.f + __expf(-a));
    }
}

// ---------------------------------------------------------------------------
extern "C" void kernel_launch(void* const* d_in, const int* in_sizes, int n_in,
                              void* d_out, int out_size, void* d_ws, size_t ws_size,
                              hipStream_t stream)
{
    const float* x     = (const float*)d_in[0];
    const float* e_w1  = (const float*)d_in[1];
    const float* e_b1  = (const float*)d_in[2];
    const float* e_w2  = (const float*)d_in[3];
    const float* e_b2  = (const float*)d_in[4];
    const float* e_w3  = (const float*)d_in[5];
    const float* e_b3  = (const float*)d_in[6];
    const float* e_w5  = (const float*)d_in[7];
    const float* e_b5  = (const float*)d_in[8];
    const float* d_w1  = (const float*)d_in[9];
    const float* d_b1  = (const float*)d_in[10];
    const float* d_w2  = (const float*)d_in[11];
    const float* d_b2  = (const float*)d_in[12];
    const float* d_w3  = (const float*)d_in[13];
    const float* d_b3  = (const float*)d_in[14];
    const float* d_w5  = (const float*)d_in[15];
    const float* d_b5  = (const float*)d_in[16];
    const float* e_wih = (const float*)d_in[17];
    const float* e_whh = (const float*)d_in[18];
    const float* e_bih = (const float*)d_in[19];
    const float* e_bhh = (const float*)d_in[20];
    const float* d_wih = (const float*)d_in[21];
    const float* d_whh = (const float*)d_in[22];
    const float* d_bih = (const float*)d_in[23];
    const float* d_bhh = (const float*)d_in[24];
    const float* a_w1  = (const float*)d_in[25];
    const float* a_b1  = (const float*)d_in[26];
    const float* a_w2  = (const float*)d_in[27];
    const float* f_w1  = (const float*)d_in[29];
    const float* f_b1  = (const float*)d_in[30];
    const float* f_w2  = (const float*)d_in[31];
    const float* f_b2  = (const float*)d_in[32];

    float* ws = (float*)d_ws;
    float* enc_feat = ws;                       // 4227072
    float* dec_feat = ws + 4227072;             // 4227072
    float* IH       = ws + 8454144;             // 16908288  (T,B,1024)
    float* conv_reg = ws + 25362432;            // 16752640
    float* hsA      = ws + 42115072;            // 32768
    float* hsB      = ws + 42147840;            // 32768
    float* cs_g     = ws + 42180608;            // 32768

    float* pool1 = conv_reg;                    // (B,64,1023)
    float* pool2 = conv_reg + 8380416;          // (B,128,255)
    float* pool3 = conv_reg + 12558336;         // (B,256,128)
    // post-conv overlays:
    float* ann      = conv_reg;                 // (B,T,256)
    float* annW     = conv_reg + 4227072;       // (B,T,256)
    float* e_wihT   = conv_reg + 8454144;       // [256][1024]
    float* d_wihT   = conv_reg + 8716288;       // [256][1024]
    float* aw1T_ann = conv_reg + 8978432;       // [256][256]
    float* aw1T_hs4 = conv_reg + 9043968;       // [k4][h][4]
    float* ctx_g    = conv_reg + 9109504;       // (B,256)
    unsigned* bars  = (unsigned*)(conv_reg + 9142272);

    dim3 blk(256);

    // ---- convnets (enc then dec) ----
    conv2k< 64, 7, 4, 2, 8, 64, true ><<<dim3(32, 128), blk, 0, stream>>>(x,     e_w1, e_b1, pool1,     64, 4096, 1023);
    conv2k< 64, 5, 4, 2, 8, 64, true ><<<dim3( 8, 128), blk, 0, stream>>>(pool1, e_w2, e_b2, pool2,    128, 1023,  255);
    conv2k<128, 3, 2, 2, 8, 64, true ><<<dim3( 2, 128), blk, 0, stream>>>(pool2, e_w3, e_b3, pool3,    256,  255,  128);
    conv2k<256, 4, 1, 2, 8, 64, false><<<dim3( 2, 128), blk, 0, stream>>>(pool3, e_w5, e_b5, enc_feat, 256,  128,  129);
    conv2k< 64, 7, 4, 2, 8, 64, true ><<<dim3(32, 128), blk, 0, stream>>>(x,     d_w1, d_b1, pool1,     64, 4096, 1023);
    conv2k< 64, 5, 4, 2, 8, 64, true ><<<dim3( 8, 128), blk, 0, stream>>>(pool1, d_w2, d_b2, pool2,    128, 1023,  255);
    conv2k<128, 3, 2, 2, 8, 64, true ><<<dim3( 2, 128), blk, 0, stream>>>(pool2, d_w3, d_b3, pool3,    256,  255,  128);
    conv2k<256, 4, 1, 2, 8, 64, false><<<dim3( 2, 128), blk, 0, stream>>>(pool3, d_w5, d_b5, dec_feat, 256,  128,  129);

    // ---- init state & barrier counters ----
    hipMemsetAsync(hsA, 0, 131072, stream);
    hipMemsetAsync(bars, 0, 256, stream);

    // ---- weight transposes (after convs; overlays are free) ----
    transpose_kt<<<dim3(1024), blk, 0, stream>>>(e_wih, e_wihT, 1024, 256, 0);
    transpose_kt<<<dim3(1024), blk, 0, stream>>>(d_wih, d_wihT, 1024, 512, 0);
    transpose_kt<<<dim3( 256), blk, 0, stream>>>(a_w1, aw1T_ann, 256, 512, 256);
    pack_aw1hs  <<<dim3( 256), blk, 0, stream>>>(a_w1, aw1T_hs4);

    // ---- encoder ----
    gemm16<1024><<<dim3(1032), blk, 0, stream>>>(enc_feat, e_wihT, e_bih, e_bhh, IH, 131072, 1024);
    enc_persist<<<dim3(256), blk, 0, stream>>>(IH, e_whh, hsA, hsB, cs_g, ann, bars);

    // ---- attention precompute + decoder IH ----
    gemm16< 256><<<dim3(1032), blk, 0, stream>>>(ann, aw1T_ann, a_b1, nullptr, annW, 256, 33024);
    gemm16<1024><<<dim3(1032), blk, 0, stream>>>(dec_feat, d_wihT, d_bih, d_bhh, IH, 131072, 1024);

    // ---- decoder (reads hsB first: encoder's final write landed there) ----
    dec_persist<<<dim3(256), blk, 0, stream>>>(IH, d_wih, d_whh, aw1T_hs4, a_w2,
                                               ann, annW, ctx_g, hsB, hsA, cs_g, bars + 32);

    // ---- head (decoder's final hs lands in hsA) ----
    final_kernel<<<dim3(128), blk, 0, stream>>>(hsA, f_w1, f_b1, f_w2, f_b2, (float*)d_out);

    (void)in_sizes; (void)n_in; (void)out_size; (void)ws_size;
}

// Round 6
// 18790.967 us; speedup vs baseline: 2.3874x; 1.0115x over previous
//
#include <hip/hip_runtime.h>
#include <cmath>

#define BN_SCALE 0.9999950000374997f

__device__ __forceinline__ float sigm(float x) { return 1.f / (1.f + __expf(-x)); }

// ---------------------------------------------------------------------------
// Conv1d (NCH) + bias + maxpool + BN-scale + ReLU, input-chunk stationary.
// grid: (ceil(Lpool/LC), B), block 256.
template<int I, int K, int POOL, int O4, int OPAR, int IC, bool ACT>
__global__ __launch_bounds__(256) void conv2k(
    const float* __restrict__ in, const float* __restrict__ w,
    const float* __restrict__ bias, float* __restrict__ out,
    int O, int Lin, int Lpool)
{
    constexpr int TLP = 256 / OPAR;
    constexpr int NLP = TLP * 4;
    constexpr int LC  = NLP / POOL;
    constexpr int SEG = NLP + K - 1;
    constexpr int PW  = O4 * OPAR;
    constexpr int ICH = I / IC;
    __shared__ float xs[IC * SEG];
    __shared__ float ws[PW * IC * K];

    const int chunk = blockIdx.x, b = blockIdx.y, tid = threadIdx.x;
    const int l0 = chunk * LC;
    const int jbase = chunk * NLP - 2;
    const int tlp = tid % TLP, og = tid / TLP;
    const int lp0 = tlp * 4;
    const int npass = O / PW;
    const float* inb = in + (size_t)b * I * Lin;

    for (int p = 0; p < npass; ++p) {
        float acc[O4][4];
        #pragma unroll
        for (int oo = 0; oo < O4; ++oo)
            #pragma unroll
            for (int j = 0; j < 4; ++j) acc[oo][j] = 0.f;

        for (int c = 0; c < ICH; ++c) {
            __syncthreads();
            for (int idx = tid; idx < PW * IC * K; idx += 256) {
                int oo = idx / (IC * K); int rem = idx % (IC * K);
                int ii = rem / K; int k = rem % K;
                ws[idx] = w[(size_t)((p * PW + oo) * I + c * IC + ii) * K + k];
            }
            if (ICH > 1 || p == 0) {
                for (int idx = tid; idx < IC * SEG; idx += 256) {
                    int ii = idx / SEG, s = idx % SEG;
                    int j = jbase + s;
                    float v = 0.f;
                    if (j >= 0 && j < Lin) v = inb[(size_t)(c * IC + ii) * Lin + j];
                    xs[idx] = v;
                }
            }
            __syncthreads();
            for (int ii = 0; ii < IC; ++ii) {
                float xv[K + 3];
                #pragma unroll
                for (int k = 0; k < K + 3; ++k) xv[k] = xs[ii * SEG + lp0 + k];
                #pragma unroll
                for (int oo = 0; oo < O4; ++oo) {
                    const float* wr = &ws[((og * O4 + oo) * IC + ii) * K];
                    #pragma unroll
                    for (int k = 0; k < K; ++k) {
                        float wv = wr[k];
                        acc[oo][0] += wv * xv[k];
                        acc[oo][1] += wv * xv[k + 1];
                        acc[oo][2] += wv * xv[k + 2];
                        acc[oo][3] += wv * xv[k + 3];
                    }
                }
            }
        }
        #pragma unroll
        for (int oo = 0; oo < O4; ++oo) {
            int o = p * PW + og * O4 + oo;
            float bv = bias[o];
            #pragma unroll
            for (int wnd = 0; wnd < 4 / POOL; ++wnd) {
                float m = acc[oo][wnd * POOL];
                #pragma unroll
                for (int q = 1; q < POOL; ++q) m = fmaxf(m, acc[oo][wnd * POOL + q]);
                int l = l0 + lp0 / POOL + wnd;
                if (l < Lpool) {
                    float v = m + bv;
                    if (ACT) v = fmaxf(v * BN_SCALE, 0.f);
                    out[((size_t)b * O + o) * Lpool + l] = v;
                }
            }
        }
    }
}

// ---------------------------------------------------------------------------
__global__ __launch_bounds__(256) void transpose_kt(
    const float* __restrict__ in, float* __restrict__ out, int N, int ldin, int off)
{
    int idx = blockIdx.x * 256 + threadIdx.x;
    int k = idx / N, n = idx % N;
    out[idx] = in[(size_t)n * ldin + off + k];
}

// ---------------------------------------------------------------------------
// OUT[t][b][n] = X[b][t*256+k] . WT[k][n] + b1[n] (+b2[n]).  K=256 fixed.
template<int N>
__global__ __launch_bounds__(256) void gemm16(
    const float* __restrict__ X, const float* __restrict__ WT,
    const float* __restrict__ b1, const float* __restrict__ b2,
    float* __restrict__ OUT, int outT, int outB)
{
    constexpr int NL = N / 4;
    constexpr int MS = N >> 6;
    __shared__ float xsh[16][257];
    const int m0 = blockIdx.x * 16;
    const int tt = m0 >> 7, bb0 = m0 & 127;
    const int tid = threadIdx.x;
    for (int it = 0; it < 16; ++it)
        xsh[it][tid] = X[(size_t)(bb0 + it) * 33024 + tt * 256 + tid];
    __syncthreads();
    const int mg = tid / NL, nl = tid % NL;
    float4 acc[MS];
    #pragma unroll
    for (int i = 0; i < MS; ++i) acc[i] = make_float4(0.f, 0.f, 0.f, 0.f);
    for (int k = 0; k < 256; ++k) {
        float4 wv = *(const float4*)(WT + (size_t)k * N + nl * 4);
        #pragma unroll
        for (int ms = 0; ms < MS; ++ms) {
            float s = xsh[mg * MS + ms][k];
            acc[ms].x += wv.x * s; acc[ms].y += wv.y * s;
            acc[ms].z += wv.z * s; acc[ms].w += wv.w * s;
        }
    }
    float4 bv = *(const float4*)(b1 + nl * 4);
    if (b2) {
        float4 b2v = *(const float4*)(b2 + nl * 4);
        bv.x += b2v.x; bv.y += b2v.y; bv.z += b2v.z; bv.w += b2v.w;
    }
    #pragma unroll
    for (int ms = 0; ms < MS; ++ms) {
        int mi = mg * MS + ms;
        float4 v = acc[ms];
        v.x += bv.x; v.y += bv.y; v.z += bv.z; v.w += bv.w;
        *(float4*)(OUT + (size_t)tt * outT + (size_t)(bb0 + mi) * outB + nl * 4) = v;
    }
}

// ---------------------------------------------------------------------------
// Encoder LSTM, one block per batch element, NO cross-block sync.
// hs in LDS, cs in registers; whh rows streamed from L2 each step.
// grid: 128, block: 1024 (thread o = gate row o).
__global__ __launch_bounds__(1024) void enc_batch(
    const float* __restrict__ IH, const float* __restrict__ whh,
    float* __restrict__ ann, float* __restrict__ hs_out, float* __restrict__ cs_out)
{
    const int b = blockIdx.x, tid = threadIdx.x;
    __shared__ float hs_l[256];
    __shared__ float g_l[1024];
    if (tid < 256) hs_l[tid] = 0.f;
    float cs_r = 0.f;
    const float4* wr = (const float4*)(whh + (size_t)tid * 256);
    __syncthreads();
    for (int t = 0; t < 129; ++t) {
        float a = IH[(size_t)t * 131072 + b * 1024 + tid];
        for (int k4 = 0; k4 < 64; ++k4) {
            float4 w4 = wr[k4];
            float4 h4 = *(const float4*)(&hs_l[k4 * 4]);
            a += w4.x * h4.x + w4.y * h4.y + w4.z * h4.z + w4.w * h4.w;
        }
        g_l[tid] = a;
        __syncthreads();
        if (tid < 256) {
            float gi = g_l[tid],       gf = g_l[256 + tid];
            float gg = g_l[512 + tid], go = g_l[768 + tid];
            float cn = sigm(gf) * cs_r + sigm(gi) * tanhf(gg);
            float hn = sigm(go) * tanhf(cn);
            cs_r = cn;
            hs_l[tid] = hn;
            ann[(size_t)b * 33024 + t * 256 + tid] = hn;
            if (t == 128) { hs_out[b * 256 + tid] = hn; cs_out[b * 256 + tid] = cn; }
        }
        __syncthreads();
    }
}

// ---------------------------------------------------------------------------
// Decoder LSTM + attention + head, one block per batch, NO cross-block sync.
// grid: 128, block: 1024.
__global__ __launch_bounds__(1024) void dec_batch(
    const float* __restrict__ IH, const float* __restrict__ dwih,
    const float* __restrict__ dwhh, const float* __restrict__ aw1,
    const float* __restrict__ aw2, const float* __restrict__ ann,
    const float* __restrict__ annW,
    const float* __restrict__ hs_in, const float* __restrict__ cs_in,
    const float* __restrict__ fw1, const float* __restrict__ fb1,
    const float* __restrict__ fw2, const float* __restrict__ fb2,
    float* __restrict__ out)
{
    const int b = blockIdx.x, tid = threadIdx.x;
    __shared__ float hs_l[256], ctx_l[256], hsW_l[256], aw2_l[256];
    __shared__ float g_l[1024], part[1024];
    __shared__ float ev_l[256], sred[256], ssum[256];
    __shared__ float inv_l;
    __shared__ float ysh[16];

    if (tid < 256) { hs_l[tid] = hs_in[b * 256 + tid]; aw2_l[tid] = aw2[tid]; }
    float cs_r = (tid < 256) ? cs_in[b * 256 + tid] : 0.f;

    const int hq = tid >> 2, qc = tid & 3;                 // hsW work split
    const float4* awr = (const float4*)(aw1 + (size_t)hq * 512 + qc * 64);
    const float4* u4 = (const float4*)(dwih + (size_t)tid * 512 + 256);
    const float4* v4 = (const float4*)(dwhh + (size_t)tid * 256);
    __syncthreads();

    for (int t = 0; t < 129; ++t) {
        // ---- phase 1: hsW[h] = a_w1[h, :256] . hs   (256 h x 4 k-chunks)
        {
            float a = 0.f;
            #pragma unroll
            for (int k4 = 0; k4 < 16; ++k4) {
                float4 w4 = awr[k4];
                float4 h4 = *(const float4*)(&hs_l[qc * 64 + k4 * 4]);
                a += w4.x * h4.x + w4.y * h4.y + w4.z * h4.z + w4.w * h4.w;
            }
            part[tid] = a;
        }
        __syncthreads();
        if (tid < 256)
            hsW_l[tid] = part[tid * 4] + part[tid * 4 + 1] + part[tid * 4 + 2] + part[tid * 4 + 3];
        __syncthreads();

        // ---- phase 2: scores s[tt] (129 tt x 4 k-chunks)
        if (tid < 516) {
            int tt = tid >> 2, c = tid & 3;
            const float4* ar = (const float4*)(annW + (size_t)b * 33024 + tt * 256 + c * 64);
            float s = 0.f;
            #pragma unroll
            for (int k4 = 0; k4 < 16; ++k4) {
                float4 av = ar[k4];
                int k = c * 64 + k4 * 4;
                s += fmaxf(hsW_l[k]     + av.x, 0.f) * aw2_l[k]
                   + fmaxf(hsW_l[k + 1] + av.y, 0.f) * aw2_l[k + 1]
                   + fmaxf(hsW_l[k + 2] + av.z, 0.f) * aw2_l[k + 2]
                   + fmaxf(hsW_l[k + 3] + av.w, 0.f) * aw2_l[k + 3];
            }
            part[tid] = s;    // a_b2 dropped: softmax shift-invariant
        }
        __syncthreads();
        float sv = -3.0e38f;
        if (tid < 129)
            sv = part[tid * 4] + part[tid * 4 + 1] + part[tid * 4 + 2] + part[tid * 4 + 3];
        if (tid < 256) sred[tid] = sv;
        __syncthreads();
        // max over 129 via one wave
        if (tid < 64) {
            float m = fmaxf(fmaxf(sred[tid], sred[tid + 64]),
                            fmaxf(sred[tid + 128], sred[tid + 192]));
            #pragma unroll
            for (int d = 32; d > 0; d >>= 1) m = fmaxf(m, __shfl_xor(m, d));
            if (tid == 0) sred[0] = m;
        }
        __syncthreads();
        const float mx = sred[0];
        float e = (tid < 129) ? __expf(sv - mx) : 0.f;
        if (tid < 256) { ev_l[tid] = e; ssum[tid] = e; }
        __syncthreads();
        if (tid < 64) {
            float s = ssum[tid] + ssum[tid + 64] + ssum[tid + 128] + ssum[tid + 192];
            #pragma unroll
            for (int d = 32; d > 0; d >>= 1) s += __shfl_xor(s, d);
            if (tid == 0) inv_l = 1.f / s;
        }
        __syncthreads();

        // ---- phase 3: ctx[j] = sum_t ev[t]*ann[b][t][j]  (256 j x 4 t-chunks)
        {
            int j = tid & 255, q = tid >> 8;
            int t0 = q * 33, t1 = t0 + 33 < 129 ? t0 + 33 : 129;
            const float* ab = ann + (size_t)b * 33024 + j;
            float a = 0.f;
            for (int t2 = t0; t2 < t1; ++t2) a += ev_l[t2] * ab[(size_t)t2 * 256];
            part[q * 256 + j] = a;
        }
        __syncthreads();
        if (tid < 256)
            ctx_l[tid] = (part[tid] + part[256 + tid] + part[512 + tid] + part[768 + tid]) * inv_l;
        __syncthreads();

        // ---- phase 4: gates (thread o streams its 2 weight rows from L2)
        {
            float a = IH[(size_t)t * 131072 + b * 1024 + tid];
            for (int k4 = 0; k4 < 64; ++k4) {
                float4 u  = u4[k4];
                float4 cv = *(const float4*)(&ctx_l[k4 * 4]);
                float4 v  = v4[k4];
                float4 hv = *(const float4*)(&hs_l[k4 * 4]);
                a += u.x * cv.x + u.y * cv.y + u.z * cv.z + u.w * cv.w;
                a += v.x * hv.x + v.y * hv.y + v.z * hv.z + v.w * hv.w;
            }
            g_l[tid] = a;
        }
        __syncthreads();
        if (tid < 256) {
            float gi = g_l[tid],       gf = g_l[256 + tid];
            float gg = g_l[512 + tid], go = g_l[768 + tid];
            float cn = sigm(gf) * cs_r + sigm(gi) * tanhf(gg);
            float hn = sigm(go) * tanhf(cn);
            cs_r = cn;
            hs_l[tid] = hn;
        }
        __syncthreads();
    }

    // ---- fused head
    if (tid < 16) {
        float a = fb1[tid];
        const float* wr = fw1 + (size_t)tid * 256;
        for (int k = 0; k < 256; ++k) a += wr[k] * hs_l[k];
        ysh[tid] = fmaxf(a, 0.f);
    }
    __syncthreads();
    if (tid < 8) {
        float a = fb2[tid];
        const float* wr = fw2 + (size_t)tid * 16;
        for (int k = 0; k < 16; ++k) a += wr[k] * ysh[k];
        out[(size_t)b * 8 + tid] = 1.f / (1.f + __expf(-a));
    }
}

// ---------------------------------------------------------------------------
extern "C" void kernel_launch(void* const* d_in, const int* in_sizes, int n_in,
                              void* d_out, int out_size, void* d_ws, size_t ws_size,
                              hipStream_t stream)
{
    const float* x     = (const float*)d_in[0];
    const float* e_w1  = (const float*)d_in[1];
    const float* e_b1  = (const float*)d_in[2];
    const float* e_w2  = (const float*)d_in[3];
    const float* e_b2  = (const float*)d_in[4];
    const float* e_w3  = (const float*)d_in[5];
    const float* e_b3  = (const float*)d_in[6];
    const float* e_w5  = (const float*)d_in[7];
    const float* e_b5  = (const float*)d_in[8];
    const float* d_w1  = (const float*)d_in[9];
    const float* d_b1  = (const float*)d_in[10];
    const float* d_w2  = (const float*)d_in[11];
    const float* d_b2  = (const float*)d_in[12];
    const float* d_w3  = (const float*)d_in[13];
    const float* d_b3  = (const float*)d_in[14];
    const float* d_w5  = (const float*)d_in[15];
    const float* d_b5  = (const float*)d_in[16];
    const float* e_wih = (const float*)d_in[17];
    const float* e_whh = (const float*)d_in[18];
    const float* e_bih = (const float*)d_in[19];
    const float* e_bhh = (const float*)d_in[20];
    const float* d_wih = (const float*)d_in[21];
    const float* d_whh = (const float*)d_in[22];
    const float* d_bih = (const float*)d_in[23];
    const float* d_bhh = (const float*)d_in[24];
    const float* a_w1  = (const float*)d_in[25];
    const float* a_b1  = (const float*)d_in[26];
    const float* a_w2  = (const float*)d_in[27];
    const float* f_w1  = (const float*)d_in[29];
    const float* f_b1  = (const float*)d_in[30];
    const float* f_w2  = (const float*)d_in[31];
    const float* f_b2  = (const float*)d_in[32];

    float* ws = (float*)d_ws;
    float* enc_feat = ws;                       // 4227072
    float* dec_feat = ws + 4227072;             // 4227072
    float* IH       = ws + 8454144;             // 16908288  (T,B,1024)
    float* conv_reg = ws + 25362432;            // 16752640
    float* hsA      = ws + 42115072;            // 32768 (encoder final hs)
    float* cs_g     = ws + 42147840;            // 32768 (encoder final cs)

    float* pool1 = conv_reg;                    // (B,64,1023)
    float* pool2 = conv_reg + 8380416;          // (B,128,255)
    float* pool3 = conv_reg + 12558336;         // (B,256,128)
    // post-conv overlays:
    float* ann      = conv_reg;                 // (B,T,256)
    float* annW     = conv_reg + 4227072;       // (B,T,256)
    float* e_wihT   = conv_reg + 8454144;       // [256][1024]
    float* d_wihT   = conv_reg + 8716288;       // [256][1024]
    float* aw1T_ann = conv_reg + 8978432;       // [256][256]

    dim3 blk(256);

    // ---- convnets (enc then dec) ----
    conv2k< 64, 7, 4, 2, 8, 64, true ><<<dim3(32, 128), blk, 0, stream>>>(x,     e_w1, e_b1, pool1,     64, 4096, 1023);
    conv2k< 64, 5, 4, 2, 8, 64, true ><<<dim3( 8, 128), blk, 0, stream>>>(pool1, e_w2, e_b2, pool2,    128, 1023,  255);
    conv2k<128, 3, 2, 2, 8, 64, true ><<<dim3( 2, 128), blk, 0, stream>>>(pool2, e_w3, e_b3, pool3,    256,  255,  128);
    conv2k<256, 4, 1, 2, 8, 64, false><<<dim3( 2, 128), blk, 0, stream>>>(pool3, e_w5, e_b5, enc_feat, 256,  128,  129);
    conv2k< 64, 7, 4, 2, 8, 64, true ><<<dim3(32, 128), blk, 0, stream>>>(x,     d_w1, d_b1, pool1,     64, 4096, 1023);
    conv2k< 64, 5, 4, 2, 8, 64, true ><<<dim3( 8, 128), blk, 0, stream>>>(pool1, d_w2, d_b2, pool2,    128, 1023,  255);
    conv2k<128, 3, 2, 2, 8, 64, true ><<<dim3( 2, 128), blk, 0, stream>>>(pool2, d_w3, d_b3, pool3,    256,  255,  128);
    conv2k<256, 4, 1, 2, 8, 64, false><<<dim3( 2, 128), blk, 0, stream>>>(pool3, d_w5, d_b5, dec_feat, 256,  128,  129);

    // ---- weight transposes (pool buffers dead now) ----
    transpose_kt<<<dim3(1024), blk, 0, stream>>>(e_wih, e_wihT, 1024, 256, 0);
    transpose_kt<<<dim3(1024), blk, 0, stream>>>(d_wih, d_wihT, 1024, 512, 0);
    transpose_kt<<<dim3( 256), blk, 0, stream>>>(a_w1, aw1T_ann, 256, 512, 256);

    // ---- encoder ----
    gemm16<1024><<<dim3(1032), blk, 0, stream>>>(enc_feat, e_wihT, e_bih, e_bhh, IH, 131072, 1024);
    enc_batch<<<dim3(128), dim3(1024), 0, stream>>>(IH, e_whh, ann, hsA, cs_g);

    // ---- attention precompute + decoder IH (IH reused after enc_batch) ----
    gemm16< 256><<<dim3(1032), blk, 0, stream>>>(ann, aw1T_ann, a_b1, nullptr, annW, 256, 33024);
    gemm16<1024><<<dim3(1032), blk, 0, stream>>>(dec_feat, d_wihT, d_bih, d_bhh, IH, 131072, 1024);

    // ---- decoder + fused head ----
    dec_batch<<<dim3(128), dim3(1024), 0, stream>>>(IH, d_wih, d_whh, a_w1, a_w2,
        ann, annW, hsA, cs_g, f_w1, f_b1, f_w2, f_b2, (float*)d_out);

    (void)in_sizes; (void)n_in; (void)out_size; (void)ws_size;
}